// Round 4
// baseline (317.398 us; speedup 1.0000x reference)
//
#include <hip/hip_runtime.h>

#define Bn 8
#define Cn 256
#define Ln 8192
#define Hn 8
#define Dn 64
#define IN 512
#define NSLAB 32

typedef __attribute__((ext_vector_type(4))) float f32x4;
typedef __attribute__((ext_vector_type(8))) __bf16 bf16x8;
typedef __attribute__((ext_vector_type(8))) unsigned short us8;

__device__ __forceinline__ float bf2f(unsigned short u) {
  unsigned int i = ((unsigned int)u) << 16;
  return __builtin_bit_cast(float, i);
}
__device__ __forceinline__ unsigned short f2bf(float f) {
  unsigned int i = __builtin_bit_cast(unsigned int, f);
  i += 0x7FFFu + ((i >> 16) & 1u);
  return (unsigned short)(i >> 16);
}
__device__ __forceinline__ bf16x8 asbf(us8 u) { return __builtin_bit_cast(bf16x8, u); }
__device__ __forceinline__ f32x4 mfma16(bf16x8 a, bf16x8 b, f32x4 c) {
  return __builtin_amdgcn_mfma_f32_16x16x32_bf16(a, b, c, 0, 0, 0);
}
__device__ __forceinline__ void gll16(const void* g, void* l) {
  __builtin_amdgcn_global_load_lds((const __attribute__((address_space(1))) void*)g,
                                   (__attribute__((address_space(3))) void*)l, 16, 0, 0);
}

// ---------------- K0a: transpose-convert x (B,C,L) f32 -> xT (B,L,C) bf16 --------
__global__ __launch_bounds__(256) void k_xt(const float* __restrict__ x,
                                            unsigned short* __restrict__ xT) {
  __shared__ unsigned short tl[64 * 66];
  const int t = threadIdx.x;
  const int l0 = blockIdx.x * 64, c0 = blockIdx.y * 64, b = blockIdx.z;
#pragma unroll
  for (int it = 0; it < 4; ++it) {
    int lin = it * 256 + t;
    int c = lin >> 4;
    int l4 = (lin & 15) * 4;
    const float* gp = x + ((size_t)(b * Cn + c0 + c) * Ln + l0 + l4);
    f32x4 v = *(const f32x4*)gp;
    unsigned int p0 = (unsigned int)f2bf(v[0]) | ((unsigned int)f2bf(v[1]) << 16);
    unsigned int p1 = (unsigned int)f2bf(v[2]) | ((unsigned int)f2bf(v[3]) << 16);
    unsigned int* d = (unsigned int*)&tl[c * 66 + l4];
    d[0] = p0;
    d[1] = p1;
  }
  __syncthreads();
#pragma unroll
  for (int it = 0; it < 2; ++it) {
    int lin = it * 256 + t;
    int l = lin >> 3;
    int s = lin & 7;
    unsigned short v[8];
#pragma unroll
    for (int j = 0; j < 8; ++j) v[j] = tl[(s * 8 + j) * 66 + l];
    uint4 pk;
    pk.x = (unsigned)v[0] | ((unsigned)v[1] << 16);
    pk.y = (unsigned)v[2] | ((unsigned)v[3] << 16);
    pk.z = (unsigned)v[4] | ((unsigned)v[5] << 16);
    pk.w = (unsigned)v[6] | ((unsigned)v[7] << 16);
    *(uint4*)&xT[(size_t)(b * Ln + l0 + l) * Cn + c0 + s * 8] = pk;
  }
}

// ---------------- K0b: convert weights to bf16 ----------------------------------
__global__ __launch_bounds__(256) void k_wcv(const float* __restrict__ Wq, const float* __restrict__ Wk,
                                             const float* __restrict__ Wv, const float* __restrict__ Wo,
                                             unsigned short* __restrict__ Wqkv,
                                             unsigned short* __restrict__ Wob) {
  int i = (blockIdx.x * 256 + threadIdx.x) * 4;
  const float* s;
  unsigned short* d;
  if (i < 393216) {
    int p = i >> 17;
    int w = i & 131071;
    s = (p == 0 ? Wq : (p == 1 ? Wk : Wv)) + w;
    d = Wqkv + i;
  } else {
    int w = i - 393216;
    s = Wo + w;
    d = Wob + w;
  }
  f32x4 v = *(const f32x4*)s;
  uint2 pk;
  pk.x = (unsigned)f2bf(v[0]) | ((unsigned)f2bf(v[1]) << 16);
  pk.y = (unsigned)f2bf(v[2]) | ((unsigned)f2bf(v[3]) << 16);
  *(uint2*)d = pk;
}

// ---------------- K1q: Q projection GEMM (m97-style staging) ---------------------
__global__ __launch_bounds__(256) void k_projq(const unsigned short* __restrict__ xT,
                                               const unsigned short* __restrict__ Wqkv,
                                               unsigned short* __restrict__ SqT) {
  __shared__ unsigned short lds[18432];
  const int tid = threadIdx.x, lane = tid & 63, wave = tid >> 6;
  const int lr = lane & 15, lg = lane >> 4;
  const int n0 = blockIdx.x * 128, m0 = blockIdx.y * 128, b = blockIdx.z;
  const int wm = (wave >> 1) * 64, wn = (wave & 1) * 64;
  unsigned short* Wt = lds;
  unsigned short* Xt = lds + 8192;

  f32x4 zero = {0.f, 0.f, 0.f, 0.f};
  f32x4 acc[4][4];
#pragma unroll
  for (int mt = 0; mt < 4; ++mt)
#pragma unroll
    for (int nt = 0; nt < 4; ++nt) acc[mt][nt] = zero;

  const int sr = tid >> 3, sc = (tid & 7) * 8;
  const unsigned short* wsrc = Wqkv + (size_t)(m0 + sr) * Cn + sc;
  const unsigned short* xsrc = xT + (size_t)(b * Ln + n0 + sr) * Cn + sc;

  for (int kt = 0; kt < 4; ++kt) {
    const int k0 = kt * 64;
#pragma unroll
    for (int it = 0; it < 4; ++it) {
      gll16(wsrc + (size_t)(it * 32) * Cn + k0, Wt + it * 2048 + tid * 8);
      gll16(xsrc + (size_t)(it * 32) * Cn + k0, Xt + it * 2048 + tid * 8);
    }
    __syncthreads();
#pragma unroll
    for (int ks = 0; ks < 2; ++ks) {
      const int kc = ks * 32 + lg * 8;
      bf16x8 af[4], bfv[4];
#pragma unroll
      for (int mt = 0; mt < 4; ++mt)
        af[mt] = asbf(*(const us8*)(Wt + (wm + mt * 16 + lr) * 64 + kc));
#pragma unroll
      for (int nt = 0; nt < 4; ++nt)
        bfv[nt] = asbf(*(const us8*)(Xt + (wn + nt * 16 + lr) * 64 + kc));
#pragma unroll
      for (int mt = 0; mt < 4; ++mt)
#pragma unroll
        for (int nt = 0; nt < 4; ++nt) acc[mt][nt] = mfma16(af[mt], bfv[nt], acc[mt][nt]);
    }
    __syncthreads();
  }

  unsigned short* T = lds + wave * 4608;  // 64x72 per-wave transpose tile
#pragma unroll
  for (int mt = 0; mt < 4; ++mt)
#pragma unroll
    for (int nt = 0; nt < 4; ++nt) {
      int ll = nt * 16 + lr, ii = mt * 16 + lg * 4;
      uint2 pk;
      pk.x = (unsigned)f2bf(acc[mt][nt][0]) | ((unsigned)f2bf(acc[mt][nt][1]) << 16);
      pk.y = (unsigned)f2bf(acc[mt][nt][2]) | ((unsigned)f2bf(acc[mt][nt][3]) << 16);
      *(uint2*)&T[ll * 72 + ii] = pk;
    }
  __syncthreads();
#pragma unroll
  for (int p = 0; p < 8; ++p) {
    int ll = p * 8 + (lane >> 3), s = lane & 7;
    uint4 v = *(const uint4*)&T[ll * 72 + s * 8];
    *(uint4*)&SqT[(size_t)(b * Ln + n0 + wn + ll) * IN + m0 + wm + s * 8] = v;
  }
}

// ---------------- K1kv: fused KV projection + exp + context (slab partials) ------
__global__ __launch_bounds__(256) void k_projkv(const unsigned short* __restrict__ xT,
                                                const unsigned short* __restrict__ Wqkv,
                                                float* __restrict__ ctxP,
                                                float* __restrict__ den) {
  __shared__ unsigned short lds[17408];  // staging 16384 || ek/vt 2*64*136
  unsigned short* Wt = lds;              // [128][64] (rows 0-63 = k-head, 64-127 = v-head)
  unsigned short* Xt = lds + 8192;       // [128][64]
  unsigned short* ek = lds;              // [64][136] exp(k) bf16, d-major
  unsigned short* vt = lds + 64 * 136;   // [64][136] v bf16, m-major
  const int tid = threadIdx.x, lane = tid & 63, wave = tid >> 6;
  const int lr = lane & 15, lg = lane >> 4;
  const int h = blockIdx.y, b = blockIdx.z;
  const int l0 = blockIdx.x * 256;
  const int wm = (wave >> 1) * 64, wn = (wave & 1) * 64;
  const int sr = tid >> 3, sc = (tid & 7) * 8;
  f32x4 zero = {0.f, 0.f, 0.f, 0.f};

  f32x4 cacc[4];
  cacc[0] = zero; cacc[1] = zero; cacc[2] = zero; cacc[3] = zero;
  float dacc[4][4] = {};

  for (int sub = 0; sub < 2; ++sub) {
    const int ls = l0 + sub * 128;
    f32x4 acc[4][4];
#pragma unroll
    for (int mt = 0; mt < 4; ++mt)
#pragma unroll
      for (int nt = 0; nt < 4; ++nt) acc[mt][nt] = zero;

    const unsigned short* xsrc = xT + (size_t)(b * Ln + ls + sr) * Cn + sc;
    for (int kt = 0; kt < 4; ++kt) {
      const int k0 = kt * 64;
#pragma unroll
      for (int it = 0; it < 4; ++it) {
        int gr = (it < 2 ? 512 : 960) + h * 64 + it * 32 + sr;  // k rows then v rows
        gll16(Wqkv + (size_t)gr * Cn + k0 + sc, Wt + it * 2048 + tid * 8);
        gll16(xsrc + (size_t)(it * 32) * Cn + k0, Xt + it * 2048 + tid * 8);
      }
      __syncthreads();
#pragma unroll
      for (int ks = 0; ks < 2; ++ks) {
        const int kc = ks * 32 + lg * 8;
        bf16x8 af[4], bfv[4];
#pragma unroll
        for (int mt = 0; mt < 4; ++mt)
          af[mt] = asbf(*(const us8*)(Wt + (wm + mt * 16 + lr) * 64 + kc));
#pragma unroll
        for (int nt = 0; nt < 4; ++nt)
          bfv[nt] = asbf(*(const us8*)(Xt + (wn + nt * 16 + lr) * 64 + kc));
#pragma unroll
        for (int mt = 0; mt < 4; ++mt)
#pragma unroll
          for (int nt = 0; nt < 4; ++nt) acc[mt][nt] = mfma16(af[mt], bfv[nt], acc[mt][nt]);
      }
      __syncthreads();
    }

    // epilogue: exp(k)->ek, v->vt (aliases staging; safe after final sync above)
    if (wave < 2) {
#pragma unroll
      for (int mt = 0; mt < 4; ++mt)
#pragma unroll
        for (int nt = 0; nt < 4; ++nt) {
          int lcol = wn + nt * 16 + lr;
#pragma unroll
          for (int r = 0; r < 4; ++r) {
            float e = __expf(acc[mt][nt][r]);
            dacc[mt][r] += e;
            ek[(mt * 16 + lg * 4 + r) * 136 + lcol] = f2bf(e);
          }
        }
    } else {
#pragma unroll
      for (int mt = 0; mt < 4; ++mt)
#pragma unroll
        for (int nt = 0; nt < 4; ++nt) {
          int lcol = wn + nt * 16 + lr;
#pragma unroll
          for (int r = 0; r < 4; ++r)
            vt[(mt * 16 + lg * 4 + r) * 136 + lcol] = f2bf(acc[mt][nt][r]);
        }
    }
    __syncthreads();

    // ctx GEMM: D[m][d] += sum_l vt[m][l] * ek[d][l], K=128
    const int mq = wave * 16;
#pragma unroll
    for (int ks = 0; ks < 4; ++ks) {
      const int kc = ks * 32 + lg * 8;
      bf16x8 a = asbf(*(const us8*)(vt + (mq + lr) * 136 + kc));
#pragma unroll
      for (int dt = 0; dt < 4; ++dt) {
        bf16x8 bb = asbf(*(const us8*)(ek + (dt * 16 + lr) * 136 + kc));
        cacc[dt] = mfma16(a, bb, cacc[dt]);
      }
    }
    __syncthreads();
  }

  // den: reduce over lr lanes, atomic per d (small: 32 atomics/block)
  if (wave < 2) {
#pragma unroll
    for (int mt = 0; mt < 4; ++mt)
#pragma unroll
      for (int r = 0; r < 4; ++r) {
        float v = dacc[mt][r];
        v += __shfl_xor(v, 1);
        v += __shfl_xor(v, 2);
        v += __shfl_xor(v, 4);
        v += __shfl_xor(v, 8);
        if (lr == 0) atomicAdd(&den[(b * Hn + h) * 64 + mt * 16 + lg * 4 + r], v);
      }
  }
  // ctx partial: private slab, plain streaming stores
  float* cb = ctxP + ((size_t)blockIdx.x * 64 + b * Hn + h) * 4096;
  const int mq = wave * 16;
#pragma unroll
  for (int dt = 0; dt < 4; ++dt)
#pragma unroll
    for (int r = 0; r < 4; ++r)
      cb[(mq + lg * 4 + r) * 64 + dt * 16 + lr] = cacc[dt][r];
}

// ---------------- K2: reduce slabs + normalize -> fragment-ready bf16 ------------
__global__ __launch_bounds__(256) void k_nrm(const float* __restrict__ ctxP,
                                             const float* __restrict__ den,
                                             unsigned short* __restrict__ ctxb) {
  const int bh = blockIdx.x, mz = blockIdx.y, t = threadIdx.x;
  const int m = mz * 16 + (t >> 4), dc = (t & 15) * 4;
  const float* base = ctxP + (size_t)bh * 4096 + m * 64 + dc;
  f32x4 s = {0.f, 0.f, 0.f, 0.f};
  for (int sl = 0; sl < NSLAB; ++sl) {
    f32x4 v = *(const f32x4*)(base + (size_t)sl * 64 * 4096);
    s += v;
  }
  f32x4 d4 = *(const f32x4*)(den + bh * 64 + dc);
  uint2 pk;
  pk.x = (unsigned)f2bf(s[0] / d4[0]) | ((unsigned)f2bf(s[1] / d4[1]) << 16);
  pk.y = (unsigned)f2bf(s[2] / d4[2]) | ((unsigned)f2bf(s[3] / d4[3]) << 16);
  *(uint2*)(ctxb + (size_t)bh * 4096 + m * 64 + dc) = pk;
}

// ---------------- K3: q-softmax + out-GEMM + output projection (2 halves) --------
__global__ __launch_bounds__(256) void k_out(const unsigned short* __restrict__ SqT,
                                             const unsigned short* __restrict__ ctxb,
                                             const unsigned short* __restrict__ Wob,
                                             const float* __restrict__ bo,
                                             float* __restrict__ out) {
  __shared__ unsigned short ot[64 * 256];  // [l][i-half] bf16, XOR-swizzled 16B slots
  const int tid = threadIdx.x, lane = tid & 63, w = tid >> 6;
  const int lr = lane & 15, lg = lane >> 4;
  const int l0 = blockIdx.x * 64, b = blockIdx.y;
  f32x4 zero = {0.f, 0.f, 0.f, 0.f};

  f32x4 acc[4][4];
#pragma unroll
  for (int mt = 0; mt < 4; ++mt)
#pragma unroll
    for (int nt = 0; nt < 4; ++nt) acc[mt][nt] = zero;

  const unsigned short* qb = SqT + (size_t)(b * Ln + l0 + w * 16 + lr) * IN + lg * 8;
  us8 r0 = *(const us8*)qb;
  us8 r1 = *(const us8*)(qb + 32);
  for (int half = 0; half < 2; ++half) {
#pragma unroll
    for (int hh = 0; hh < 4; ++hh) {
      const int h = half * 4 + hh;
      us8 n0, n1;
      if (h < 7) {
        n0 = *(const us8*)(qb + (h + 1) * 64);
        n1 = *(const us8*)(qb + (h + 1) * 64 + 32);
      }
      float qv[16];
#pragma unroll
      for (int j = 0; j < 8; ++j) {
        qv[j] = bf2f(r0[j]);
        qv[8 + j] = bf2f(r1[j]);
      }
      float mx = qv[0];
#pragma unroll
      for (int j = 1; j < 16; ++j) mx = fmaxf(mx, qv[j]);
      mx = fmaxf(mx, __shfl_xor(mx, 16));
      mx = fmaxf(mx, __shfl_xor(mx, 32));
      float sm = 0.f;
#pragma unroll
      for (int j = 0; j < 16; ++j) {
        qv[j] = __expf(qv[j] - mx);
        sm += qv[j];
      }
      sm += __shfl_xor(sm, 16);
      sm += __shfl_xor(sm, 32);
      float rs = 1.0f / sm;
      us8 a0u, a1u;
#pragma unroll
      for (int j = 0; j < 8; ++j) {
        a0u[j] = f2bf(qv[j] * rs);
        a1u[j] = f2bf(qv[8 + j] * rs);
      }
      bf16x8 a0 = asbf(a0u), a1 = asbf(a1u);
      const unsigned short* cbb = ctxb + (size_t)(b * Hn + h) * 4096;
#pragma unroll
      for (int mt = 0; mt < 4; ++mt) {
        bf16x8 bu0 = asbf(*(const us8*)(cbb + (mt * 16 + lr) * 64 + lg * 8));
        bf16x8 bu1 = asbf(*(const us8*)(cbb + (mt * 16 + lr) * 64 + 32 + lg * 8));
        f32x4 oa = mfma16(a0, bu0, zero);
        oa = mfma16(a1, bu1, oa);
        int ib = hh * 64 + mt * 16 + lr;
#pragma unroll
        for (int r = 0; r < 4; ++r) {
          int ll = w * 16 + lg * 4 + r;
          ot[(ll * 256 + ib) ^ ((ll & 7) << 3)] = f2bf(oa[r]);
        }
      }
      r0 = n0;
      r1 = n1;
    }
    __syncthreads();

    const unsigned short* wB = Wob + (size_t)(w * 64 + lr) * IN + half * 256;
#pragma unroll 2
    for (int ks = 0; ks < 8; ++ks) {
      int kc = ks * 32 + lg * 8;
      bf16x8 af[4], bf4[4];
#pragma unroll
      for (int mt = 0; mt < 4; ++mt) af[mt] = asbf(*(const us8*)(wB + mt * 16 * IN + kc));
#pragma unroll
      for (int nt = 0; nt < 4; ++nt) {
        int ll = nt * 16 + lr;
        bf4[nt] = asbf(*(const us8*)&ot[(ll * 256 + kc) ^ ((ll & 7) << 3)]);
      }
#pragma unroll
      for (int mt = 0; mt < 4; ++mt)
#pragma unroll
        for (int nt = 0; nt < 4; ++nt) acc[mt][nt] = mfma16(af[mt], bf4[nt], acc[mt][nt]);
    }
    __syncthreads();
  }
#pragma unroll
  for (int mt = 0; mt < 4; ++mt) {
    int c = w * 64 + mt * 16 + lg * 4;
#pragma unroll
    for (int r = 0; r < 4; ++r) {
      float bb = bo[c + r];
      float* op = out + (size_t)(b * Cn + c + r) * Ln + l0;
#pragma unroll
      for (int nt = 0; nt < 4; ++nt) op[nt * 16 + lr] = acc[mt][nt][r] + bb;
    }
  }
}

extern "C" void kernel_launch(void* const* d_in, const int* in_sizes, int n_in,
                              void* d_out, int out_size, void* d_ws, size_t ws_size,
                              hipStream_t stream) {
  const float* x = (const float*)d_in[0];
  const float* Wq = (const float*)d_in[1];
  const float* Wk = (const float*)d_in[2];
  const float* Wv = (const float*)d_in[3];
  const float* Wo = (const float*)d_in[4];
  const float* bo = (const float*)d_in[5];
  float* out = (float*)d_out;

  char* ws = (char*)d_ws;
  size_t o = 0;
  unsigned short* xT = (unsigned short*)(ws + o);   o += (size_t)Bn * Ln * Cn * 2;   // 33.5 MB
  unsigned short* Wqkv = (unsigned short*)(ws + o); o += (size_t)1536 * Cn * 2;      // 768 KB
  unsigned short* Wob = (unsigned short*)(ws + o);  o += (size_t)Cn * IN * 2;        // 256 KB
  unsigned short* SqT = (unsigned short*)(ws + o);  o += (size_t)Bn * Ln * IN * 2;   // 67 MB
  float* ctxP = (float*)(ws + o);                   o += (size_t)NSLAB * 64 * 4096 * 4;  // 33.5 MB
  float* den = (float*)(ws + o);                    o += (size_t)Bn * Hn * 64 * 4;       // 16 KB
  unsigned short* ctxb = (unsigned short*)(ws + o); o += (size_t)Bn * Hn * 64 * 64 * 2;  // 0.5 MB

  hipMemsetAsync(den, 0, (size_t)Bn * Hn * 64 * 4, stream);
  k_xt<<<dim3(Ln / 64, Cn / 64, Bn), 256, 0, stream>>>(x, xT);
  k_wcv<<<512, 256, 0, stream>>>(Wq, Wk, Wv, Wo, Wqkv, Wob);
  k_projq<<<dim3(Ln / 128, 4, Bn), 256, 0, stream>>>(xT, Wqkv, SqT);
  k_projkv<<<dim3(Ln / 256, Hn, Bn), 256, 0, stream>>>(xT, Wqkv, ctxP, den);
  k_nrm<<<dim3(Bn * Hn, 4), 256, 0, stream>>>(ctxP, den, ctxb);
  k_out<<<dim3(Ln / 64, Bn), 256, 0, stream>>>(SqT, ctxb, Wob, bo, out);
}

// Round 5
// 297.497 us; speedup vs baseline: 1.0669x; 1.0669x over previous
//
#include <hip/hip_runtime.h>

#define Bn 8
#define Cn 256
#define Ln 8192
#define Hn 8
#define Dn 64
#define IN 512
#define NSLAB 16

typedef __attribute__((ext_vector_type(4))) float f32x4;
typedef __attribute__((ext_vector_type(8))) __bf16 bf16x8;
typedef __attribute__((ext_vector_type(8))) unsigned short us8;

__device__ __forceinline__ float bf2f(unsigned short u) {
  unsigned int i = ((unsigned int)u) << 16;
  return __builtin_bit_cast(float, i);
}
__device__ __forceinline__ unsigned short f2bf(float f) {
  unsigned int i = __builtin_bit_cast(unsigned int, f);
  i += 0x7FFFu + ((i >> 16) & 1u);
  return (unsigned short)(i >> 16);
}
__device__ __forceinline__ bf16x8 asbf(us8 u) { return __builtin_bit_cast(bf16x8, u); }
__device__ __forceinline__ f32x4 mfma16(bf16x8 a, bf16x8 b, f32x4 c) {
  return __builtin_amdgcn_mfma_f32_16x16x32_bf16(a, b, c, 0, 0, 0);
}
__device__ __forceinline__ void gll16(const void* g, void* l) {
  __builtin_amdgcn_global_load_lds((const __attribute__((address_space(1))) void*)g,
                                   (__attribute__((address_space(3))) void*)l, 16, 0, 0);
}

// ---------------- K0a: transpose-convert x (B,C,L) f32 -> xT (B,L,C) bf16 --------
__global__ __launch_bounds__(256) void k_xt(const float* __restrict__ x,
                                            unsigned short* __restrict__ xT) {
  __shared__ unsigned short tl[64 * 66];
  const int t = threadIdx.x;
  const int l0 = blockIdx.x * 64, c0 = blockIdx.y * 64, b = blockIdx.z;
#pragma unroll
  for (int it = 0; it < 4; ++it) {
    int lin = it * 256 + t;
    int c = lin >> 4;
    int l4 = (lin & 15) * 4;
    const float* gp = x + ((size_t)(b * Cn + c0 + c) * Ln + l0 + l4);
    f32x4 v = *(const f32x4*)gp;
    unsigned int p0 = (unsigned int)f2bf(v[0]) | ((unsigned int)f2bf(v[1]) << 16);
    unsigned int p1 = (unsigned int)f2bf(v[2]) | ((unsigned int)f2bf(v[3]) << 16);
    unsigned int* d = (unsigned int*)&tl[c * 66 + l4];
    d[0] = p0;
    d[1] = p1;
  }
  __syncthreads();
#pragma unroll
  for (int it = 0; it < 2; ++it) {
    int lin = it * 256 + t;
    int l = lin >> 3;
    int s = lin & 7;
    unsigned short v[8];
#pragma unroll
    for (int j = 0; j < 8; ++j) v[j] = tl[(s * 8 + j) * 66 + l];
    uint4 pk;
    pk.x = (unsigned)v[0] | ((unsigned)v[1] << 16);
    pk.y = (unsigned)v[2] | ((unsigned)v[3] << 16);
    pk.z = (unsigned)v[4] | ((unsigned)v[5] << 16);
    pk.w = (unsigned)v[6] | ((unsigned)v[7] << 16);
    *(uint4*)&xT[(size_t)(b * Ln + l0 + l) * Cn + c0 + s * 8] = pk;
  }
}

// ---------------- K0b: convert weights to bf16 ----------------------------------
__global__ __launch_bounds__(256) void k_wcv(const float* __restrict__ Wq, const float* __restrict__ Wk,
                                             const float* __restrict__ Wv, const float* __restrict__ Wo,
                                             unsigned short* __restrict__ Wqkv,
                                             unsigned short* __restrict__ Wob) {
  int i = (blockIdx.x * 256 + threadIdx.x) * 4;
  const float* s;
  unsigned short* d;
  if (i < 393216) {
    int p = i >> 17;
    int w = i & 131071;
    s = (p == 0 ? Wq : (p == 1 ? Wk : Wv)) + w;
    d = Wqkv + i;
  } else {
    int w = i - 393216;
    s = Wo + w;
    d = Wob + w;
  }
  f32x4 v = *(const f32x4*)s;
  uint2 pk;
  pk.x = (unsigned)f2bf(v[0]) | ((unsigned)f2bf(v[1]) << 16);
  pk.y = (unsigned)f2bf(v[2]) | ((unsigned)f2bf(v[3]) << 16);
  *(uint2*)d = pk;
}

// ---------------- K1q: Q projection GEMM (m97-style staging) ---------------------
__global__ __launch_bounds__(256) void k_projq(const unsigned short* __restrict__ xT,
                                               const unsigned short* __restrict__ Wqkv,
                                               unsigned short* __restrict__ SqT) {
  __shared__ unsigned short lds[18432];
  const int tid = threadIdx.x, lane = tid & 63, wave = tid >> 6;
  const int lr = lane & 15, lg = lane >> 4;
  const int n0 = blockIdx.x * 128, m0 = blockIdx.y * 128, b = blockIdx.z;
  const int wm = (wave >> 1) * 64, wn = (wave & 1) * 64;
  unsigned short* Wt = lds;
  unsigned short* Xt = lds + 8192;

  f32x4 zero = {0.f, 0.f, 0.f, 0.f};
  f32x4 acc[4][4];
#pragma unroll
  for (int mt = 0; mt < 4; ++mt)
#pragma unroll
    for (int nt = 0; nt < 4; ++nt) acc[mt][nt] = zero;

  const int sr = tid >> 3, sc = (tid & 7) * 8;
  const unsigned short* wsrc = Wqkv + (size_t)(m0 + sr) * Cn + sc;
  const unsigned short* xsrc = xT + (size_t)(b * Ln + n0 + sr) * Cn + sc;

  for (int kt = 0; kt < 4; ++kt) {
    const int k0 = kt * 64;
#pragma unroll
    for (int it = 0; it < 4; ++it) {
      gll16(wsrc + (size_t)(it * 32) * Cn + k0, Wt + it * 2048 + tid * 8);
      gll16(xsrc + (size_t)(it * 32) * Cn + k0, Xt + it * 2048 + tid * 8);
    }
    __syncthreads();
#pragma unroll
    for (int ks = 0; ks < 2; ++ks) {
      const int kc = ks * 32 + lg * 8;
      bf16x8 af[4], bfv[4];
#pragma unroll
      for (int mt = 0; mt < 4; ++mt)
        af[mt] = asbf(*(const us8*)(Wt + (wm + mt * 16 + lr) * 64 + kc));
#pragma unroll
      for (int nt = 0; nt < 4; ++nt)
        bfv[nt] = asbf(*(const us8*)(Xt + (wn + nt * 16 + lr) * 64 + kc));
#pragma unroll
      for (int mt = 0; mt < 4; ++mt)
#pragma unroll
        for (int nt = 0; nt < 4; ++nt) acc[mt][nt] = mfma16(af[mt], bfv[nt], acc[mt][nt]);
    }
    __syncthreads();
  }

  unsigned short* T = lds + wave * 4608;  // 64x72 per-wave transpose tile
#pragma unroll
  for (int mt = 0; mt < 4; ++mt)
#pragma unroll
    for (int nt = 0; nt < 4; ++nt) {
      int ll = nt * 16 + lr, ii = mt * 16 + lg * 4;
      uint2 pk;
      pk.x = (unsigned)f2bf(acc[mt][nt][0]) | ((unsigned)f2bf(acc[mt][nt][1]) << 16);
      pk.y = (unsigned)f2bf(acc[mt][nt][2]) | ((unsigned)f2bf(acc[mt][nt][3]) << 16);
      *(uint2*)&T[ll * 72 + ii] = pk;
    }
  __syncthreads();
#pragma unroll
  for (int p = 0; p < 8; ++p) {
    int ll = p * 8 + (lane >> 3), s = lane & 7;
    uint4 v = *(const uint4*)&T[ll * 72 + s * 8];
    *(uint4*)&SqT[(size_t)(b * Ln + n0 + wn + ll) * IN + m0 + wm + s * 8] = v;
  }
}

// ---------------- K1kv: fused KV projection + exp + context (slab partials) ------
__global__ __launch_bounds__(256) void k_projkv(const unsigned short* __restrict__ xT,
                                                const unsigned short* __restrict__ Wqkv,
                                                float* __restrict__ ctxP,
                                                float* __restrict__ den) {
  __shared__ unsigned short lds[17408];  // staging 16384 || ek/vt 2*64*136
  unsigned short* Wt = lds;              // [128][64] (rows 0-63 = k-head, 64-127 = v-head)
  unsigned short* Xt = lds + 8192;       // [128][64]
  unsigned short* ek = lds;              // [64][136] exp(k) bf16, d-major
  unsigned short* vt = lds + 64 * 136;   // [64][136] v bf16, m-major
  const int tid = threadIdx.x, lane = tid & 63, wave = tid >> 6;
  const int lr = lane & 15, lg = lane >> 4;
  const int h = blockIdx.y, b = blockIdx.z;
  const int l0 = blockIdx.x * 512;
  const int wm = (wave >> 1) * 64, wn = (wave & 1) * 64;
  const int sr = tid >> 3, sc = (tid & 7) * 8;
  f32x4 zero = {0.f, 0.f, 0.f, 0.f};

  f32x4 cacc[4];
  cacc[0] = zero; cacc[1] = zero; cacc[2] = zero; cacc[3] = zero;
  float dacc[4][4] = {};

  for (int sub = 0; sub < 4; ++sub) {
    const int ls = l0 + sub * 128;
    f32x4 acc[4][4];
#pragma unroll
    for (int mt = 0; mt < 4; ++mt)
#pragma unroll
      for (int nt = 0; nt < 4; ++nt) acc[mt][nt] = zero;

    const unsigned short* xsrc = xT + (size_t)(b * Ln + ls + sr) * Cn + sc;
    for (int kt = 0; kt < 4; ++kt) {
      const int k0 = kt * 64;
#pragma unroll
      for (int it = 0; it < 4; ++it) {
        int gr = (it < 2 ? 512 : 960) + h * 64 + it * 32 + sr;  // k rows then v rows
        gll16(Wqkv + (size_t)gr * Cn + k0 + sc, Wt + it * 2048 + tid * 8);
        gll16(xsrc + (size_t)(it * 32) * Cn + k0, Xt + it * 2048 + tid * 8);
      }
      __syncthreads();
#pragma unroll
      for (int ks = 0; ks < 2; ++ks) {
        const int kc = ks * 32 + lg * 8;
        bf16x8 af[4], bfv[4];
#pragma unroll
        for (int mt = 0; mt < 4; ++mt)
          af[mt] = asbf(*(const us8*)(Wt + (wm + mt * 16 + lr) * 64 + kc));
#pragma unroll
        for (int nt = 0; nt < 4; ++nt)
          bfv[nt] = asbf(*(const us8*)(Xt + (wn + nt * 16 + lr) * 64 + kc));
#pragma unroll
        for (int mt = 0; mt < 4; ++mt)
#pragma unroll
          for (int nt = 0; nt < 4; ++nt) acc[mt][nt] = mfma16(af[mt], bfv[nt], acc[mt][nt]);
      }
      __syncthreads();
    }

    // epilogue: exp(k)->ek, v->vt (aliases staging; safe after final sync above)
    if (wave < 2) {
#pragma unroll
      for (int mt = 0; mt < 4; ++mt)
#pragma unroll
        for (int nt = 0; nt < 4; ++nt) {
          int lcol = wn + nt * 16 + lr;
#pragma unroll
          for (int r = 0; r < 4; ++r) {
            float e = __expf(acc[mt][nt][r]);
            dacc[mt][r] += e;
            ek[(mt * 16 + lg * 4 + r) * 136 + lcol] = f2bf(e);
          }
        }
    } else {
#pragma unroll
      for (int mt = 0; mt < 4; ++mt)
#pragma unroll
        for (int nt = 0; nt < 4; ++nt) {
          int lcol = wn + nt * 16 + lr;
#pragma unroll
          for (int r = 0; r < 4; ++r)
            vt[(mt * 16 + lg * 4 + r) * 136 + lcol] = f2bf(acc[mt][nt][r]);
        }
    }
    __syncthreads();

    // ctx GEMM: D[m][d] += sum_l vt[m][l] * ek[d][l], K=128
    const int mq = wave * 16;
#pragma unroll
    for (int ks = 0; ks < 4; ++ks) {
      const int kc = ks * 32 + lg * 8;
      bf16x8 a = asbf(*(const us8*)(vt + (mq + lr) * 136 + kc));
#pragma unroll
      for (int dt = 0; dt < 4; ++dt) {
        bf16x8 bb = asbf(*(const us8*)(ek + (dt * 16 + lr) * 136 + kc));
        cacc[dt] = mfma16(a, bb, cacc[dt]);
      }
    }
    __syncthreads();
  }

  // den: reduce over lr lanes, atomic per d (small: 32 atomics/block)
  if (wave < 2) {
#pragma unroll
    for (int mt = 0; mt < 4; ++mt)
#pragma unroll
      for (int r = 0; r < 4; ++r) {
        float v = dacc[mt][r];
        v += __shfl_xor(v, 1);
        v += __shfl_xor(v, 2);
        v += __shfl_xor(v, 4);
        v += __shfl_xor(v, 8);
        if (lr == 0) atomicAdd(&den[(b * Hn + h) * 64 + mt * 16 + lg * 4 + r], v);
      }
  }
  // ctx partial: private slab, plain streaming stores
  float* cb = ctxP + ((size_t)blockIdx.x * 64 + b * Hn + h) * 4096;
  const int mq = wave * 16;
#pragma unroll
  for (int dt = 0; dt < 4; ++dt)
#pragma unroll
    for (int r = 0; r < 4; ++r)
      cb[(mq + lg * 4 + r) * 64 + dt * 16 + lr] = cacc[dt][r];
}

// ---------------- K2: reduce slabs + normalize -> fragment-ready bf16 ------------
__global__ __launch_bounds__(256) void k_nrm(const float* __restrict__ ctxP,
                                             const float* __restrict__ den,
                                             unsigned short* __restrict__ ctxb) {
  const int bh = blockIdx.x, mz = blockIdx.y, t = threadIdx.x;
  const int m = mz * 16 + (t >> 4), dc = (t & 15) * 4;
  const float* base = ctxP + (size_t)bh * 4096 + m * 64 + dc;
  f32x4 s = {0.f, 0.f, 0.f, 0.f};
  for (int sl = 0; sl < NSLAB; ++sl) {
    f32x4 v = *(const f32x4*)(base + (size_t)sl * 64 * 4096);
    s += v;
  }
  f32x4 d4 = *(const f32x4*)(den + bh * 64 + dc);
  uint2 pk;
  pk.x = (unsigned)f2bf(s[0] / d4[0]) | ((unsigned)f2bf(s[1] / d4[1]) << 16);
  pk.y = (unsigned)f2bf(s[2] / d4[2]) | ((unsigned)f2bf(s[3] / d4[3]) << 16);
  *(uint2*)(ctxb + (size_t)bh * 4096 + m * 64 + dc) = pk;
}

// ---------------- K3: q-softmax + out-GEMM + output projection (8 waves) ---------
__global__ __launch_bounds__(512) void k_out(const unsigned short* __restrict__ SqT,
                                             const unsigned short* __restrict__ ctxb,
                                             const unsigned short* __restrict__ Wob,
                                             const float* __restrict__ bo,
                                             float* __restrict__ out) {
  __shared__ unsigned short ot[64 * IN];  // [l][i] bf16, XOR-swizzled 16B slots
  const int tid = threadIdx.x, lane = tid & 63, w = tid >> 6;
  const int wg = w >> 2, wi = w & 3;  // half, wave-within-half
  const int lr = lane & 15, lg = lane >> 4;
  const int l0 = blockIdx.x * 64, b = blockIdx.y;
  f32x4 zero = {0.f, 0.f, 0.f, 0.f};

  // ---- softmax + ctx GEMM: wave (wg,wi) handles heads wg*4+0..3, rows wi*16+lr --
  const unsigned short* qb =
      SqT + (size_t)(b * Ln + l0 + wi * 16 + lr) * IN + wg * 4 * 64 + lg * 8;
  us8 r0 = *(const us8*)qb;
  us8 r1 = *(const us8*)(qb + 32);
#pragma unroll
  for (int hh = 0; hh < 4; ++hh) {
    const int h = wg * 4 + hh;
    us8 n0, n1;
    if (hh < 3) {
      n0 = *(const us8*)(qb + (hh + 1) * 64);
      n1 = *(const us8*)(qb + (hh + 1) * 64 + 32);
    }
    float qv[16];
#pragma unroll
    for (int j = 0; j < 8; ++j) {
      qv[j] = bf2f(r0[j]);
      qv[8 + j] = bf2f(r1[j]);
    }
    float mx = qv[0];
#pragma unroll
    for (int j = 1; j < 16; ++j) mx = fmaxf(mx, qv[j]);
    mx = fmaxf(mx, __shfl_xor(mx, 16));
    mx = fmaxf(mx, __shfl_xor(mx, 32));
    float sm = 0.f;
#pragma unroll
    for (int j = 0; j < 16; ++j) {
      qv[j] = __expf(qv[j] - mx);
      sm += qv[j];
    }
    sm += __shfl_xor(sm, 16);
    sm += __shfl_xor(sm, 32);
    float rs = 1.0f / sm;
    us8 a0u, a1u;
#pragma unroll
    for (int j = 0; j < 8; ++j) {
      a0u[j] = f2bf(qv[j] * rs);
      a1u[j] = f2bf(qv[8 + j] * rs);
    }
    bf16x8 a0 = asbf(a0u), a1 = asbf(a1u);
    const unsigned short* cbb = ctxb + (size_t)(b * Hn + h) * 4096;
#pragma unroll
    for (int mt = 0; mt < 4; ++mt) {
      bf16x8 bu0 = asbf(*(const us8*)(cbb + (mt * 16 + lr) * 64 + lg * 8));
      bf16x8 bu1 = asbf(*(const us8*)(cbb + (mt * 16 + lr) * 64 + 32 + lg * 8));
      f32x4 oa = mfma16(a0, bu0, zero);
      oa = mfma16(a1, bu1, oa);
      int ib = h * 64 + mt * 16 + lr;
#pragma unroll
      for (int r = 0; r < 4; ++r) {
        int ll = wi * 16 + lg * 4 + r;
        ot[(ll * IN + ib) ^ ((ll & 7) << 3)] = f2bf(oa[r]);
      }
    }
    r0 = n0;
    r1 = n1;
  }
  __syncthreads();

  // ---- Wo GEMM: 8 waves, M=32/wave, N=64, K=512 ---------------------------------
  f32x4 acc[2][4];
#pragma unroll
  for (int mt = 0; mt < 2; ++mt)
#pragma unroll
    for (int nt = 0; nt < 4; ++nt) acc[mt][nt] = zero;
  const unsigned short* wB = Wob + (size_t)(w * 32 + lr) * IN;
#pragma unroll 4
  for (int ks = 0; ks < 16; ++ks) {
    int kc = ks * 32 + lg * 8;
    bf16x8 af[2], bf4[4];
#pragma unroll
    for (int mt = 0; mt < 2; ++mt) af[mt] = asbf(*(const us8*)(wB + mt * 16 * IN + kc));
#pragma unroll
    for (int nt = 0; nt < 4; ++nt) {
      int ll = nt * 16 + lr;
      bf4[nt] = asbf(*(const us8*)&ot[(ll * IN + kc) ^ ((ll & 7) << 3)]);
    }
#pragma unroll
    for (int mt = 0; mt < 2; ++mt)
#pragma unroll
      for (int nt = 0; nt < 4; ++nt) acc[mt][nt] = mfma16(af[mt], bf4[nt], acc[mt][nt]);
  }
#pragma unroll
  for (int mt = 0; mt < 2; ++mt) {
    int c = w * 32 + mt * 16 + lg * 4;
#pragma unroll
    for (int r = 0; r < 4; ++r) {
      float bb = bo[c + r];
      float* op = out + (size_t)(b * Cn + c + r) * Ln + l0;
#pragma unroll
      for (int nt = 0; nt < 4; ++nt) op[nt * 16 + lr] = acc[mt][nt][r] + bb;
    }
  }
}

extern "C" void kernel_launch(void* const* d_in, const int* in_sizes, int n_in,
                              void* d_out, int out_size, void* d_ws, size_t ws_size,
                              hipStream_t stream) {
  const float* x = (const float*)d_in[0];
  const float* Wq = (const float*)d_in[1];
  const float* Wk = (const float*)d_in[2];
  const float* Wv = (const float*)d_in[3];
  const float* Wo = (const float*)d_in[4];
  const float* bo = (const float*)d_in[5];
  float* out = (float*)d_out;

  char* ws = (char*)d_ws;
  size_t o = 0;
  unsigned short* xT = (unsigned short*)(ws + o);   o += (size_t)Bn * Ln * Cn * 2;   // 33.5 MB
  unsigned short* Wqkv = (unsigned short*)(ws + o); o += (size_t)1536 * Cn * 2;      // 768 KB
  unsigned short* Wob = (unsigned short*)(ws + o);  o += (size_t)Cn * IN * 2;        // 256 KB
  unsigned short* SqT = (unsigned short*)(ws + o);  o += (size_t)Bn * Ln * IN * 2;   // 67 MB
  float* ctxP = (float*)(ws + o);                   o += (size_t)NSLAB * 64 * 4096 * 4;  // 16.8 MB
  float* den = (float*)(ws + o);                    o += (size_t)Bn * Hn * 64 * 4;       // 16 KB
  unsigned short* ctxb = (unsigned short*)(ws + o); o += (size_t)Bn * Hn * 64 * 64 * 2;  // 0.5 MB

  hipMemsetAsync(den, 0, (size_t)Bn * Hn * 64 * 4, stream);
  k_xt<<<dim3(Ln / 64, Cn / 64, Bn), 256, 0, stream>>>(x, xT);
  k_wcv<<<512, 256, 0, stream>>>(Wq, Wk, Wv, Wo, Wqkv, Wob);
  k_projq<<<dim3(Ln / 128, 4, Bn), 256, 0, stream>>>(xT, Wqkv, SqT);
  k_projkv<<<dim3(Ln / 512, Hn, Bn), 256, 0, stream>>>(xT, Wqkv, ctxP, den);
  k_nrm<<<dim3(Bn * Hn, 4), 256, 0, stream>>>(ctxP, den, ctxb);
  k_out<<<dim3(Ln / 64, Bn), 512, 0, stream>>>(SqT, ctxb, Wob, bo, out);
}

// Round 6
// 271.791 us; speedup vs baseline: 1.1678x; 1.0946x over previous
//
#include <hip/hip_runtime.h>

#define Bn 8
#define Cn 256
#define Ln 8192
#define Hn 8
#define Dn 64
#define IN 512
#define NSLAB 16

typedef __attribute__((ext_vector_type(4))) float f32x4;
typedef __attribute__((ext_vector_type(8))) __bf16 bf16x8;
typedef __attribute__((ext_vector_type(8))) unsigned short us8;

__device__ __forceinline__ float bf2f(unsigned short u) {
  unsigned int i = ((unsigned int)u) << 16;
  return __builtin_bit_cast(float, i);
}
__device__ __forceinline__ unsigned short f2bf(float f) {
  unsigned int i = __builtin_bit_cast(unsigned int, f);
  i += 0x7FFFu + ((i >> 16) & 1u);
  return (unsigned short)(i >> 16);
}
__device__ __forceinline__ bf16x8 asbf(us8 u) { return __builtin_bit_cast(bf16x8, u); }
__device__ __forceinline__ f32x4 mfma16(bf16x8 a, bf16x8 b, f32x4 c) {
  return __builtin_amdgcn_mfma_f32_16x16x32_bf16(a, b, c, 0, 0, 0);
}
__device__ __forceinline__ void gll16(const void* g, void* l) {
  __builtin_amdgcn_global_load_lds((const __attribute__((address_space(1))) void*)g,
                                   (__attribute__((address_space(3))) void*)l, 16, 0, 0);
}

// ---------------- K0a: transpose-convert x (B,C,L) f32 -> xT (B,L,C) bf16 --------
__global__ __launch_bounds__(256) void k_xt(const float* __restrict__ x,
                                            unsigned short* __restrict__ xT) {
  __shared__ unsigned short tl[64 * 66];
  const int t = threadIdx.x;
  const int l0 = blockIdx.x * 64, c0 = blockIdx.y * 64, b = blockIdx.z;
#pragma unroll
  for (int it = 0; it < 4; ++it) {
    int lin = it * 256 + t;
    int c = lin >> 4;
    int l4 = (lin & 15) * 4;
    const float* gp = x + ((size_t)(b * Cn + c0 + c) * Ln + l0 + l4);
    f32x4 v = *(const f32x4*)gp;
    unsigned int p0 = (unsigned int)f2bf(v[0]) | ((unsigned int)f2bf(v[1]) << 16);
    unsigned int p1 = (unsigned int)f2bf(v[2]) | ((unsigned int)f2bf(v[3]) << 16);
    unsigned int* d = (unsigned int*)&tl[c * 66 + l4];
    d[0] = p0;
    d[1] = p1;
  }
  __syncthreads();
#pragma unroll
  for (int it = 0; it < 2; ++it) {
    int lin = it * 256 + t;
    int l = lin >> 3;
    int s = lin & 7;
    unsigned short v[8];
#pragma unroll
    for (int j = 0; j < 8; ++j) v[j] = tl[(s * 8 + j) * 66 + l];
    uint4 pk;
    pk.x = (unsigned)v[0] | ((unsigned)v[1] << 16);
    pk.y = (unsigned)v[2] | ((unsigned)v[3] << 16);
    pk.z = (unsigned)v[4] | ((unsigned)v[5] << 16);
    pk.w = (unsigned)v[6] | ((unsigned)v[7] << 16);
    *(uint4*)&xT[(size_t)(b * Ln + l0 + l) * Cn + c0 + s * 8] = pk;
  }
}

// ---------------- K0b: convert weights to bf16 ----------------------------------
__global__ __launch_bounds__(256) void k_wcv(const float* __restrict__ Wq, const float* __restrict__ Wk,
                                             const float* __restrict__ Wv, const float* __restrict__ Wo,
                                             unsigned short* __restrict__ Wqkv,
                                             unsigned short* __restrict__ Wob) {
  int i = (blockIdx.x * 256 + threadIdx.x) * 4;
  const float* s;
  unsigned short* d;
  if (i < 393216) {
    int p = i >> 17;
    int w = i & 131071;
    s = (p == 0 ? Wq : (p == 1 ? Wk : Wv)) + w;
    d = Wqkv + i;
  } else {
    int w = i - 393216;
    s = Wo + w;
    d = Wob + w;
  }
  f32x4 v = *(const f32x4*)s;
  uint2 pk;
  pk.x = (unsigned)f2bf(v[0]) | ((unsigned)f2bf(v[1]) << 16);
  pk.y = (unsigned)f2bf(v[2]) | ((unsigned)f2bf(v[3]) << 16);
  *(uint2*)d = pk;
}

// ---------------- K1q: Q projection + in-register softmax -> qhT (B,L,512) -------
__global__ __launch_bounds__(256) void k_qs(const unsigned short* __restrict__ xT,
                                            const unsigned short* __restrict__ Wqkv,
                                            unsigned short* __restrict__ qhT) {
  __shared__ unsigned short lds[18432];
  const int tid = threadIdx.x, lane = tid & 63, wave = tid >> 6;
  const int lr = lane & 15, lg = lane >> 4;
  const int n0 = blockIdx.x * 128, m0 = blockIdx.y * 128, b = blockIdx.z;
  const int wm = (wave >> 1) * 64, wn = (wave & 1) * 64;
  unsigned short* Wt = lds;
  unsigned short* Xt = lds + 8192;

  f32x4 zero = {0.f, 0.f, 0.f, 0.f};
  f32x4 acc[4][4];
#pragma unroll
  for (int mt = 0; mt < 4; ++mt)
#pragma unroll
    for (int nt = 0; nt < 4; ++nt) acc[mt][nt] = zero;

  const int sr = tid >> 3, sc = (tid & 7) * 8;
  const unsigned short* wsrc = Wqkv + (size_t)(m0 + sr) * Cn + sc;
  const unsigned short* xsrc = xT + (size_t)(b * Ln + n0 + sr) * Cn + sc;

  for (int kt = 0; kt < 4; ++kt) {
    const int k0 = kt * 64;
#pragma unroll
    for (int it = 0; it < 4; ++it) {
      gll16(wsrc + (size_t)(it * 32) * Cn + k0, Wt + it * 2048 + tid * 8);
      gll16(xsrc + (size_t)(it * 32) * Cn + k0, Xt + it * 2048 + tid * 8);
    }
    __syncthreads();
#pragma unroll
    for (int ks = 0; ks < 2; ++ks) {
      const int kc = ks * 32 + lg * 8;
      bf16x8 af[4], bfv[4];
#pragma unroll
      for (int mt = 0; mt < 4; ++mt)
        af[mt] = asbf(*(const us8*)(Wt + (wm + mt * 16 + lr) * 64 + kc));
#pragma unroll
      for (int nt = 0; nt < 4; ++nt)
        bfv[nt] = asbf(*(const us8*)(Xt + (wn + nt * 16 + lr) * 64 + kc));
#pragma unroll
      for (int mt = 0; mt < 4; ++mt)
#pragma unroll
        for (int nt = 0; nt < 4; ++nt) acc[mt][nt] = mfma16(af[mt], bfv[nt], acc[mt][nt]);
    }
    __syncthreads();
  }

  // epilogue: per l-column softmax over the wave's 64 i-rows (one full head),
  // then bf16 pack into per-wave transpose tile T[l][i] and coalesced store.
  unsigned short* T = lds + wave * 4608;
#pragma unroll
  for (int nt = 0; nt < 4; ++nt) {
    float qv[16];
#pragma unroll
    for (int mt = 0; mt < 4; ++mt)
#pragma unroll
      for (int r = 0; r < 4; ++r) qv[mt * 4 + r] = acc[mt][nt][r];
    float mx = qv[0];
#pragma unroll
    for (int j = 1; j < 16; ++j) mx = fmaxf(mx, qv[j]);
    mx = fmaxf(mx, __shfl_xor(mx, 16));
    mx = fmaxf(mx, __shfl_xor(mx, 32));
    float sm = 0.f;
#pragma unroll
    for (int j = 0; j < 16; ++j) {
      qv[j] = __expf(qv[j] - mx);
      sm += qv[j];
    }
    sm += __shfl_xor(sm, 16);
    sm += __shfl_xor(sm, 32);
    float rs = 1.0f / sm;
    int ll = nt * 16 + lr;
#pragma unroll
    for (int mt = 0; mt < 4; ++mt) {
      uint2 pk;
      pk.x = (unsigned)f2bf(qv[mt * 4 + 0] * rs) | ((unsigned)f2bf(qv[mt * 4 + 1] * rs) << 16);
      pk.y = (unsigned)f2bf(qv[mt * 4 + 2] * rs) | ((unsigned)f2bf(qv[mt * 4 + 3] * rs) << 16);
      *(uint2*)&T[ll * 72 + mt * 16 + lg * 4] = pk;
    }
  }
  __syncthreads();
#pragma unroll
  for (int p = 0; p < 8; ++p) {
    int ll = p * 8 + (lane >> 3), s = lane & 7;
    uint4 v = *(const uint4*)&T[ll * 72 + s * 8];
    *(uint4*)&qhT[(size_t)(b * Ln + n0 + wn + ll) * IN + m0 + wm + s * 8] = v;
  }
}

// ---------------- K1kv: fused KV projection + exp + context (slab partials) ------
__global__ __launch_bounds__(256) void k_projkv(const unsigned short* __restrict__ xT,
                                                const unsigned short* __restrict__ Wqkv,
                                                float* __restrict__ ctxP,
                                                float* __restrict__ den) {
  __shared__ unsigned short lds[17408];  // staging 16384 || ek/vt 2*64*136
  unsigned short* Wt = lds;              // [128][64] (rows 0-63 = k-head, 64-127 = v-head)
  unsigned short* Xt = lds + 8192;       // [128][64]
  unsigned short* ek = lds;              // [64][136] exp(k) bf16, d-major
  unsigned short* vt = lds + 64 * 136;   // [64][136] v bf16, m-major
  const int tid = threadIdx.x, lane = tid & 63, wave = tid >> 6;
  const int lr = lane & 15, lg = lane >> 4;
  const int h = blockIdx.y, b = blockIdx.z;
  const int l0 = blockIdx.x * 512;
  const int wm = (wave >> 1) * 64, wn = (wave & 1) * 64;
  const int sr = tid >> 3, sc = (tid & 7) * 8;
  f32x4 zero = {0.f, 0.f, 0.f, 0.f};

  f32x4 cacc[4];
  cacc[0] = zero; cacc[1] = zero; cacc[2] = zero; cacc[3] = zero;
  float dacc[4][4] = {};

  for (int sub = 0; sub < 4; ++sub) {
    const int ls = l0 + sub * 128;
    f32x4 acc[4][4];
#pragma unroll
    for (int mt = 0; mt < 4; ++mt)
#pragma unroll
      for (int nt = 0; nt < 4; ++nt) acc[mt][nt] = zero;

    const unsigned short* xsrc = xT + (size_t)(b * Ln + ls + sr) * Cn + sc;
    for (int kt = 0; kt < 4; ++kt) {
      const int k0 = kt * 64;
#pragma unroll
      for (int it = 0; it < 4; ++it) {
        int gr = (it < 2 ? 512 : 960) + h * 64 + it * 32 + sr;  // k rows then v rows
        gll16(Wqkv + (size_t)gr * Cn + k0 + sc, Wt + it * 2048 + tid * 8);
        gll16(xsrc + (size_t)(it * 32) * Cn + k0, Xt + it * 2048 + tid * 8);
      }
      __syncthreads();
#pragma unroll
      for (int ks = 0; ks < 2; ++ks) {
        const int kc = ks * 32 + lg * 8;
        bf16x8 af[4], bfv[4];
#pragma unroll
        for (int mt = 0; mt < 4; ++mt)
          af[mt] = asbf(*(const us8*)(Wt + (wm + mt * 16 + lr) * 64 + kc));
#pragma unroll
        for (int nt = 0; nt < 4; ++nt)
          bfv[nt] = asbf(*(const us8*)(Xt + (wn + nt * 16 + lr) * 64 + kc));
#pragma unroll
        for (int mt = 0; mt < 4; ++mt)
#pragma unroll
          for (int nt = 0; nt < 4; ++nt) acc[mt][nt] = mfma16(af[mt], bfv[nt], acc[mt][nt]);
      }
      __syncthreads();
    }

    // epilogue: exp(k)->ek, v->vt (aliases staging; safe after final sync above)
    if (wave < 2) {
#pragma unroll
      for (int mt = 0; mt < 4; ++mt)
#pragma unroll
        for (int nt = 0; nt < 4; ++nt) {
          int lcol = wn + nt * 16 + lr;
#pragma unroll
          for (int r = 0; r < 4; ++r) {
            float e = __expf(acc[mt][nt][r]);
            dacc[mt][r] += e;
            ek[(mt * 16 + lg * 4 + r) * 136 + lcol] = f2bf(e);
          }
        }
    } else {
#pragma unroll
      for (int mt = 0; mt < 4; ++mt)
#pragma unroll
        for (int nt = 0; nt < 4; ++nt) {
          int lcol = wn + nt * 16 + lr;
#pragma unroll
          for (int r = 0; r < 4; ++r)
            vt[(mt * 16 + lg * 4 + r) * 136 + lcol] = f2bf(acc[mt][nt][r]);
        }
    }
    __syncthreads();

    // ctx GEMM: D[m][d] += sum_l vt[m][l] * ek[d][l], K=128
    const int mq = wave * 16;
#pragma unroll
    for (int ks = 0; ks < 4; ++ks) {
      const int kc = ks * 32 + lg * 8;
      bf16x8 a = asbf(*(const us8*)(vt + (mq + lr) * 136 + kc));
#pragma unroll
      for (int dt = 0; dt < 4; ++dt) {
        bf16x8 bb = asbf(*(const us8*)(ek + (dt * 16 + lr) * 136 + kc));
        cacc[dt] = mfma16(a, bb, cacc[dt]);
      }
    }
    __syncthreads();
  }

  // den: reduce over lr lanes, atomic per d (small: 32 atomics/block)
  if (wave < 2) {
#pragma unroll
    for (int mt = 0; mt < 4; ++mt)
#pragma unroll
      for (int r = 0; r < 4; ++r) {
        float v = dacc[mt][r];
        v += __shfl_xor(v, 1);
        v += __shfl_xor(v, 2);
        v += __shfl_xor(v, 4);
        v += __shfl_xor(v, 8);
        if (lr == 0) atomicAdd(&den[(b * Hn + h) * 64 + mt * 16 + lg * 4 + r], v);
      }
  }
  // ctx partial: private slab, plain streaming stores
  float* cb = ctxP + ((size_t)blockIdx.x * 64 + b * Hn + h) * 4096;
  const int mq = wave * 16;
#pragma unroll
  for (int dt = 0; dt < 4; ++dt)
#pragma unroll
    for (int r = 0; r < 4; ++r)
      cb[(mq + lg * 4 + r) * 64 + dt * 16 + lr] = cacc[dt][r];
}

// ---------------- K2: reduce slabs + normalize + transpose -> ctxdm [bh][d][m] ---
__global__ __launch_bounds__(256) void k_nrm(const float* __restrict__ ctxP,
                                             const float* __restrict__ den,
                                             unsigned short* __restrict__ ctxdm) {
  const int bh = blockIdx.x, t = threadIdx.x;
  const int m = t >> 2, dq = (t & 3) * 16;
  const float* base = ctxP + (size_t)bh * 4096 + m * 64 + dq;
  const float* dnb = den + bh * 64 + dq;
#pragma unroll
  for (int q = 0; q < 4; ++q) {
    f32x4 s = {0.f, 0.f, 0.f, 0.f};
    for (int sl = 0; sl < NSLAB; ++sl) s += *(const f32x4*)(base + (size_t)sl * 64 * 4096 + q * 4);
    f32x4 d4 = *(const f32x4*)(dnb + q * 4);
#pragma unroll
    for (int j = 0; j < 4; ++j)
      ctxdm[(size_t)bh * 4096 + (dq + q * 4 + j) * 64 + m] = f2bf(s[j] / d4[j]);
  }
}

// ---------------- K2b: fold Wo with normalized context ---------------------------
// Wfold[b][c][h*64+d] = sum_m Wob[c][h*64+m] * ctxdm[b][h][d][m]
__global__ __launch_bounds__(256) void k_fold(const unsigned short* __restrict__ Wob,
                                              const unsigned short* __restrict__ ctxdm,
                                              unsigned short* __restrict__ Wfold) {
  const int tid = threadIdx.x, lane = tid & 63, wave = tid >> 6;
  const int lr = lane & 15, lg = lane >> 4;
  const int h = blockIdx.x, b = blockIdx.y;
  const int c0 = wave * 64;
  f32x4 zero = {0.f, 0.f, 0.f, 0.f};
  f32x4 acc[4][4];
#pragma unroll
  for (int mt = 0; mt < 4; ++mt)
#pragma unroll
    for (int nt = 0; nt < 4; ++nt) acc[mt][nt] = zero;
  const unsigned short* cdb = ctxdm + (size_t)(b * Hn + h) * 4096;
#pragma unroll
  for (int ks = 0; ks < 2; ++ks) {
    const int kc = ks * 32 + lg * 8;
    bf16x8 af[4], bf4[4];
#pragma unroll
    for (int mt = 0; mt < 4; ++mt)
      af[mt] = asbf(*(const us8*)(Wob + (size_t)(c0 + mt * 16 + lr) * IN + h * 64 + kc));
#pragma unroll
    for (int nt = 0; nt < 4; ++nt)
      bf4[nt] = asbf(*(const us8*)(cdb + (nt * 16 + lr) * 64 + kc));
#pragma unroll
    for (int mt = 0; mt < 4; ++mt)
#pragma unroll
      for (int nt = 0; nt < 4; ++nt) acc[mt][nt] = mfma16(af[mt], bf4[nt], acc[mt][nt]);
  }
  unsigned short* wf = Wfold + (size_t)b * Cn * IN;
#pragma unroll
  for (int mt = 0; mt < 4; ++mt)
#pragma unroll
    for (int nt = 0; nt < 4; ++nt) {
      int c = c0 + mt * 16 + lg * 4;
      int d = h * 64 + nt * 16 + lr;
#pragma unroll
      for (int r = 0; r < 4; ++r) wf[(size_t)(c + r) * IN + d] = f2bf(acc[mt][nt][r]);
    }
}

// ---------------- K3: out = Wfold @ qhT^T + bo (m97-style GEMM) ------------------
__global__ __launch_bounds__(256) void k_wo(const unsigned short* __restrict__ qhT,
                                            const unsigned short* __restrict__ Wfold,
                                            const float* __restrict__ bo,
                                            float* __restrict__ out) {
  __shared__ unsigned short lds[16384];
  const int tid = threadIdx.x, lane = tid & 63, wave = tid >> 6;
  const int lr = lane & 15, lg = lane >> 4;
  const int gl = blockIdx.x * 128;
  const int b = gl >> 13, l0 = gl & 8191;
  const int m0 = blockIdx.y * 128;
  const int wm = (wave >> 1) * 64, wn = (wave & 1) * 64;
  unsigned short* Wt = lds;
  unsigned short* Qt = lds + 8192;

  f32x4 zero = {0.f, 0.f, 0.f, 0.f};
  f32x4 acc[4][4];
#pragma unroll
  for (int mt = 0; mt < 4; ++mt)
#pragma unroll
    for (int nt = 0; nt < 4; ++nt) acc[mt][nt] = zero;

  const int sr = tid >> 3, sc = (tid & 7) * 8;
  const unsigned short* wsrc = Wfold + (size_t)b * Cn * IN + (size_t)(m0 + sr) * IN + sc;
  const unsigned short* qsrc = qhT + (size_t)(b * Ln + l0 + sr) * IN + sc;

  for (int kt = 0; kt < 8; ++kt) {
    const int k0 = kt * 64;
#pragma unroll
    for (int it = 0; it < 4; ++it) {
      gll16(wsrc + (size_t)(it * 32) * IN + k0, Wt + it * 2048 + tid * 8);
      gll16(qsrc + (size_t)(it * 32) * IN + k0, Qt + it * 2048 + tid * 8);
    }
    __syncthreads();
#pragma unroll
    for (int ks = 0; ks < 2; ++ks) {
      const int kc = ks * 32 + lg * 8;
      bf16x8 af[4], bfv[4];
#pragma unroll
      for (int mt = 0; mt < 4; ++mt)
        af[mt] = asbf(*(const us8*)(Wt + (wm + mt * 16 + lr) * 64 + kc));
#pragma unroll
      for (int nt = 0; nt < 4; ++nt)
        bfv[nt] = asbf(*(const us8*)(Qt + (wn + nt * 16 + lr) * 64 + kc));
#pragma unroll
      for (int mt = 0; mt < 4; ++mt)
#pragma unroll
        for (int nt = 0; nt < 4; ++nt) acc[mt][nt] = mfma16(af[mt], bfv[nt], acc[mt][nt]);
    }
    __syncthreads();
  }

#pragma unroll
  for (int mt = 0; mt < 4; ++mt) {
    int c = m0 + wm + mt * 16 + lg * 4;
#pragma unroll
    for (int r = 0; r < 4; ++r) {
      float bb = bo[c + r];
      float* op = out + (size_t)(b * Cn + c + r) * Ln + l0 + wn;
#pragma unroll
      for (int nt = 0; nt < 4; ++nt) op[nt * 16 + lr] = acc[mt][nt][r] + bb;
    }
  }
}

extern "C" void kernel_launch(void* const* d_in, const int* in_sizes, int n_in,
                              void* d_out, int out_size, void* d_ws, size_t ws_size,
                              hipStream_t stream) {
  const float* x = (const float*)d_in[0];
  const float* Wq = (const float*)d_in[1];
  const float* Wk = (const float*)d_in[2];
  const float* Wv = (const float*)d_in[3];
  const float* Wo = (const float*)d_in[4];
  const float* bo = (const float*)d_in[5];
  float* out = (float*)d_out;

  char* ws = (char*)d_ws;
  size_t o = 0;
  unsigned short* xT = (unsigned short*)(ws + o);    o += (size_t)Bn * Ln * Cn * 2;   // 33.5 MB
  unsigned short* Wqkv = (unsigned short*)(ws + o);  o += (size_t)1536 * Cn * 2;      // 768 KB
  unsigned short* Wob = (unsigned short*)(ws + o);   o += (size_t)Cn * IN * 2;        // 256 KB
  unsigned short* qhT = (unsigned short*)(ws + o);   o += (size_t)Bn * Ln * IN * 2;   // 67 MB
  float* ctxP = (float*)(ws + o);                    o += (size_t)NSLAB * 64 * 4096 * 4;  // 16.8 MB
  float* den = (float*)(ws + o);                     o += (size_t)Bn * Hn * 64 * 4;       // 16 KB
  unsigned short* ctxdm = (unsigned short*)(ws + o); o += (size_t)Bn * Hn * 64 * 64 * 2;  // 0.5 MB
  unsigned short* Wfold = (unsigned short*)(ws + o); o += (size_t)Bn * Cn * IN * 2;       // 2 MB

  hipMemsetAsync(den, 0, (size_t)Bn * Hn * 64 * 4, stream);
  k_xt<<<dim3(Ln / 64, Cn / 64, Bn), 256, 0, stream>>>(x, xT);
  k_wcv<<<512, 256, 0, stream>>>(Wq, Wk, Wv, Wo, Wqkv, Wob);
  k_qs<<<dim3(Ln / 128, 4, Bn), 256, 0, stream>>>(xT, Wqkv, qhT);
  k_projkv<<<dim3(Ln / 512, Hn, Bn), 256, 0, stream>>>(xT, Wqkv, ctxP, den);
  k_nrm<<<Bn * Hn, 256, 0, stream>>>(ctxP, den, ctxdm);
  k_fold<<<dim3(Hn, Bn), 256, 0, stream>>>(Wob, ctxdm, Wfold);
  k_wo<<<dim3(Bn * Ln / 128, 2), 256, 0, stream>>>(qhT, Wfold, bo, out);
}

// Round 7
// 269.491 us; speedup vs baseline: 1.1778x; 1.0085x over previous
//
#include <hip/hip_runtime.h>

#define Bn 8
#define Cn 256
#define Ln 8192
#define Hn 8
#define Dn 64
#define IN 512
#define NSLAB 16

typedef __attribute__((ext_vector_type(4))) float f32x4;
typedef __attribute__((ext_vector_type(8))) __bf16 bf16x8;
typedef __attribute__((ext_vector_type(8))) unsigned short us8;

__device__ __forceinline__ float bf2f(unsigned short u) {
  unsigned int i = ((unsigned int)u) << 16;
  return __builtin_bit_cast(float, i);
}
__device__ __forceinline__ unsigned short f2bf(float f) {
  unsigned int i = __builtin_bit_cast(unsigned int, f);
  i += 0x7FFFu + ((i >> 16) & 1u);
  return (unsigned short)(i >> 16);
}
__device__ __forceinline__ bf16x8 asbf(us8 u) { return __builtin_bit_cast(bf16x8, u); }
__device__ __forceinline__ f32x4 mfma16(bf16x8 a, bf16x8 b, f32x4 c) {
  return __builtin_amdgcn_mfma_f32_16x16x32_bf16(a, b, c, 0, 0, 0);
}
__device__ __forceinline__ void gll16(const void* g, void* l) {
  __builtin_amdgcn_global_load_lds((const __attribute__((address_space(1))) void*)g,
                                   (__attribute__((address_space(3))) void*)l, 16, 0, 0);
}

// ---------------- K0a: transpose-convert x (B,C,L) f32 -> xT (B,L,C) bf16 --------
__global__ __launch_bounds__(256) void k_xt(const float* __restrict__ x,
                                            unsigned short* __restrict__ xT) {
  __shared__ unsigned short tl[64 * 66];
  const int t = threadIdx.x;
  const int l0 = blockIdx.x * 64, c0 = blockIdx.y * 64, b = blockIdx.z;
#pragma unroll
  for (int it = 0; it < 4; ++it) {
    int lin = it * 256 + t;
    int c = lin >> 4;
    int l4 = (lin & 15) * 4;
    const float* gp = x + ((size_t)(b * Cn + c0 + c) * Ln + l0 + l4);
    f32x4 v = *(const f32x4*)gp;
    unsigned int p0 = (unsigned int)f2bf(v[0]) | ((unsigned int)f2bf(v[1]) << 16);
    unsigned int p1 = (unsigned int)f2bf(v[2]) | ((unsigned int)f2bf(v[3]) << 16);
    unsigned int* d = (unsigned int*)&tl[c * 66 + l4];
    d[0] = p0;
    d[1] = p1;
  }
  __syncthreads();
#pragma unroll
  for (int it = 0; it < 2; ++it) {
    int lin = it * 256 + t;
    int l = lin >> 3;
    int s = lin & 7;
    unsigned short v[8];
#pragma unroll
    for (int j = 0; j < 8; ++j) v[j] = tl[(s * 8 + j) * 66 + l];
    uint4 pk;
    pk.x = (unsigned)v[0] | ((unsigned)v[1] << 16);
    pk.y = (unsigned)v[2] | ((unsigned)v[3] << 16);
    pk.z = (unsigned)v[4] | ((unsigned)v[5] << 16);
    pk.w = (unsigned)v[6] | ((unsigned)v[7] << 16);
    *(uint4*)&xT[(size_t)(b * Ln + l0 + l) * Cn + c0 + s * 8] = pk;
  }
}

// ---------------- K0b: convert weights to bf16 ----------------------------------
__global__ __launch_bounds__(256) void k_wcv(const float* __restrict__ Wq, const float* __restrict__ Wk,
                                             const float* __restrict__ Wv, const float* __restrict__ Wo,
                                             unsigned short* __restrict__ Wqkv,
                                             unsigned short* __restrict__ Wob) {
  int i = (blockIdx.x * 256 + threadIdx.x) * 4;
  const float* s;
  unsigned short* d;
  if (i < 393216) {
    int p = i >> 17;
    int w = i & 131071;
    s = (p == 0 ? Wq : (p == 1 ? Wk : Wv)) + w;
    d = Wqkv + i;
  } else {
    int w = i - 393216;
    s = Wo + w;
    d = Wob + w;
  }
  f32x4 v = *(const f32x4*)s;
  uint2 pk;
  pk.x = (unsigned)f2bf(v[0]) | ((unsigned)f2bf(v[1]) << 16);
  pk.y = (unsigned)f2bf(v[2]) | ((unsigned)f2bf(v[3]) << 16);
  *(uint2*)d = pk;
}

// ---------------- K1q: Q projection + in-register softmax -> qhT (B,L,512) -------
// Staging LDS is XOR-swizzled: LDS slot [row][s] holds global col-slot s^(row&7).
__global__ __launch_bounds__(256) void k_qs(const unsigned short* __restrict__ xT,
                                            const unsigned short* __restrict__ Wqkv,
                                            unsigned short* __restrict__ qhT) {
  __shared__ unsigned short lds[18432];
  const int tid = threadIdx.x, lane = tid & 63, wave = tid >> 6;
  const int lr = lane & 15, lg = lane >> 4;
  const int n0 = blockIdx.x * 128, m0 = blockIdx.y * 128, b = blockIdx.z;
  const int wm = (wave >> 1) * 64, wn = (wave & 1) * 64;
  unsigned short* Wt = lds;
  unsigned short* Xt = lds + 8192;

  f32x4 zero = {0.f, 0.f, 0.f, 0.f};
  f32x4 acc[4][4];
#pragma unroll
  for (int mt = 0; mt < 4; ++mt)
#pragma unroll
    for (int nt = 0; nt < 4; ++nt) acc[mt][nt] = zero;

  const int sr = tid >> 3;
  const int scw = (((tid & 7) ^ (sr & 7)) << 3);  // swizzled source col
  const int rx = (lr & 7);                        // read-side row XOR key
  const unsigned short* wsrc = Wqkv + (size_t)(m0 + sr) * Cn + scw;
  const unsigned short* xsrc = xT + (size_t)(b * Ln + n0 + sr) * Cn + scw;

  for (int kt = 0; kt < 4; ++kt) {
    const int k0 = kt * 64;
#pragma unroll
    for (int it = 0; it < 4; ++it) {
      gll16(wsrc + (size_t)(it * 32) * Cn + k0, Wt + it * 2048 + tid * 8);
      gll16(xsrc + (size_t)(it * 32) * Cn + k0, Xt + it * 2048 + tid * 8);
    }
    __syncthreads();
#pragma unroll
    for (int ks = 0; ks < 2; ++ks) {
      const int kc = ((ks * 4 + lg) ^ rx) << 3;  // swizzled read col
      bf16x8 af[4], bfv[4];
#pragma unroll
      for (int mt = 0; mt < 4; ++mt)
        af[mt] = asbf(*(const us8*)(Wt + (wm + mt * 16 + lr) * 64 + kc));
#pragma unroll
      for (int nt = 0; nt < 4; ++nt)
        bfv[nt] = asbf(*(const us8*)(Xt + (wn + nt * 16 + lr) * 64 + kc));
#pragma unroll
      for (int mt = 0; mt < 4; ++mt)
#pragma unroll
        for (int nt = 0; nt < 4; ++nt) acc[mt][nt] = mfma16(af[mt], bfv[nt], acc[mt][nt]);
    }
    __syncthreads();
  }

  // epilogue: per l-column softmax over the wave's 64 i-rows (one full head),
  // then bf16 pack into per-wave transpose tile T[l][i] and coalesced store.
  unsigned short* T = lds + wave * 4608;
#pragma unroll
  for (int nt = 0; nt < 4; ++nt) {
    float qv[16];
#pragma unroll
    for (int mt = 0; mt < 4; ++mt)
#pragma unroll
      for (int r = 0; r < 4; ++r) qv[mt * 4 + r] = acc[mt][nt][r];
    float mx = qv[0];
#pragma unroll
    for (int j = 1; j < 16; ++j) mx = fmaxf(mx, qv[j]);
    mx = fmaxf(mx, __shfl_xor(mx, 16));
    mx = fmaxf(mx, __shfl_xor(mx, 32));
    float sm = 0.f;
#pragma unroll
    for (int j = 0; j < 16; ++j) {
      qv[j] = __expf(qv[j] - mx);
      sm += qv[j];
    }
    sm += __shfl_xor(sm, 16);
    sm += __shfl_xor(sm, 32);
    float rs = 1.0f / sm;
    int ll = nt * 16 + lr;
#pragma unroll
    for (int mt = 0; mt < 4; ++mt) {
      uint2 pk;
      pk.x = (unsigned)f2bf(qv[mt * 4 + 0] * rs) | ((unsigned)f2bf(qv[mt * 4 + 1] * rs) << 16);
      pk.y = (unsigned)f2bf(qv[mt * 4 + 2] * rs) | ((unsigned)f2bf(qv[mt * 4 + 3] * rs) << 16);
      *(uint2*)&T[ll * 72 + mt * 16 + lg * 4] = pk;
    }
  }
  __syncthreads();
#pragma unroll
  for (int p = 0; p < 8; ++p) {
    int ll = p * 8 + (lane >> 3), s = lane & 7;
    uint4 v = *(const uint4*)&T[ll * 72 + s * 8];
    *(uint4*)&qhT[(size_t)(b * Ln + n0 + wn + ll) * IN + m0 + wm + s * 8] = v;
  }
}

// ---------------- K1kv: fused KV projection + exp + context (slab partials) ------
__global__ __launch_bounds__(256) void k_projkv(const unsigned short* __restrict__ xT,
                                                const unsigned short* __restrict__ Wqkv,
                                                float* __restrict__ ctxP,
                                                float* __restrict__ den) {
  __shared__ unsigned short lds[17408];  // staging 16384 || ek/vt 2*64*136
  unsigned short* Wt = lds;              // [128][64] (rows 0-63 = k-head, 64-127 = v-head)
  unsigned short* Xt = lds + 8192;       // [128][64]
  unsigned short* ek = lds;              // [64][136] exp(k) bf16, d-major
  unsigned short* vt = lds + 64 * 136;   // [64][136] v bf16, m-major
  const int tid = threadIdx.x, lane = tid & 63, wave = tid >> 6;
  const int lr = lane & 15, lg = lane >> 4;
  const int h = blockIdx.y, b = blockIdx.z;
  const int l0 = blockIdx.x * 512;
  const int wm = (wave >> 1) * 64, wn = (wave & 1) * 64;
  const int sr = tid >> 3;
  const int scw = (((tid & 7) ^ (sr & 7)) << 3);
  const int rx = (lr & 7);
  f32x4 zero = {0.f, 0.f, 0.f, 0.f};

  f32x4 cacc[4];
  cacc[0] = zero; cacc[1] = zero; cacc[2] = zero; cacc[3] = zero;
  float dacc[4][4] = {};

  for (int sub = 0; sub < 4; ++sub) {
    const int ls = l0 + sub * 128;
    f32x4 acc[4][4];
#pragma unroll
    for (int mt = 0; mt < 4; ++mt)
#pragma unroll
      for (int nt = 0; nt < 4; ++nt) acc[mt][nt] = zero;

    const unsigned short* xsrc = xT + (size_t)(b * Ln + ls + sr) * Cn + scw;
    for (int kt = 0; kt < 4; ++kt) {
      const int k0 = kt * 64;
#pragma unroll
      for (int it = 0; it < 4; ++it) {
        int gr = (it < 2 ? 512 : 960) + h * 64 + it * 32 + sr;  // k rows then v rows
        gll16(Wqkv + (size_t)gr * Cn + k0 + scw, Wt + it * 2048 + tid * 8);
        gll16(xsrc + (size_t)(it * 32) * Cn + k0, Xt + it * 2048 + tid * 8);
      }
      __syncthreads();
#pragma unroll
      for (int ks = 0; ks < 2; ++ks) {
        const int kc = ((ks * 4 + lg) ^ rx) << 3;
        bf16x8 af[4], bfv[4];
#pragma unroll
        for (int mt = 0; mt < 4; ++mt)
          af[mt] = asbf(*(const us8*)(Wt + (wm + mt * 16 + lr) * 64 + kc));
#pragma unroll
        for (int nt = 0; nt < 4; ++nt)
          bfv[nt] = asbf(*(const us8*)(Xt + (wn + nt * 16 + lr) * 64 + kc));
#pragma unroll
        for (int mt = 0; mt < 4; ++mt)
#pragma unroll
          for (int nt = 0; nt < 4; ++nt) acc[mt][nt] = mfma16(af[mt], bfv[nt], acc[mt][nt]);
      }
      __syncthreads();
    }

    // epilogue: exp(k)->ek, v->vt (aliases staging; safe after final sync above)
    if (wave < 2) {
#pragma unroll
      for (int mt = 0; mt < 4; ++mt)
#pragma unroll
        for (int nt = 0; nt < 4; ++nt) {
          int lcol = wn + nt * 16 + lr;
#pragma unroll
          for (int r = 0; r < 4; ++r) {
            float e = __expf(acc[mt][nt][r]);
            dacc[mt][r] += e;
            ek[(mt * 16 + lg * 4 + r) * 136 + lcol] = f2bf(e);
          }
        }
    } else {
#pragma unroll
      for (int mt = 0; mt < 4; ++mt)
#pragma unroll
        for (int nt = 0; nt < 4; ++nt) {
          int lcol = wn + nt * 16 + lr;
#pragma unroll
          for (int r = 0; r < 4; ++r)
            vt[(mt * 16 + lg * 4 + r) * 136 + lcol] = f2bf(acc[mt][nt][r]);
        }
    }
    __syncthreads();

    // ctx GEMM: D[m][d] += sum_l vt[m][l] * ek[d][l], K=128
    const int mq = wave * 16;
#pragma unroll
    for (int ks = 0; ks < 4; ++ks) {
      const int kc = ks * 32 + lg * 8;
      bf16x8 a = asbf(*(const us8*)(vt + (mq + lr) * 136 + kc));
#pragma unroll
      for (int dt = 0; dt < 4; ++dt) {
        bf16x8 bb = asbf(*(const us8*)(ek + (dt * 16 + lr) * 136 + kc));
        cacc[dt] = mfma16(a, bb, cacc[dt]);
      }
    }
    __syncthreads();
  }

  // den: reduce over lr lanes, atomic per d (small: 32 atomics/block)
  if (wave < 2) {
#pragma unroll
    for (int mt = 0; mt < 4; ++mt)
#pragma unroll
      for (int r = 0; r < 4; ++r) {
        float v = dacc[mt][r];
        v += __shfl_xor(v, 1);
        v += __shfl_xor(v, 2);
        v += __shfl_xor(v, 4);
        v += __shfl_xor(v, 8);
        if (lr == 0) atomicAdd(&den[(b * Hn + h) * 64 + mt * 16 + lg * 4 + r], v);
      }
  }
  // ctx partial: private slab, plain streaming stores
  float* cb = ctxP + ((size_t)blockIdx.x * 64 + b * Hn + h) * 4096;
  const int mq = wave * 16;
#pragma unroll
  for (int dt = 0; dt < 4; ++dt)
#pragma unroll
    for (int r = 0; r < 4; ++r)
      cb[(mq + lg * 4 + r) * 64 + dt * 16 + lr] = cacc[dt][r];
}

// ---------------- K2: reduce slabs + normalize + transpose -> ctxdm [bh][d][m] ---
__global__ __launch_bounds__(256) void k_nrm(const float* __restrict__ ctxP,
                                             const float* __restrict__ den,
                                             unsigned short* __restrict__ ctxdm) {
  const int bh = blockIdx.x, t = threadIdx.x;
  const int m = t >> 2, dq = (t & 3) * 16;
  const float* base = ctxP + (size_t)bh * 4096 + m * 64 + dq;
  const float* dnb = den + bh * 64 + dq;
#pragma unroll
  for (int q = 0; q < 4; ++q) {
    f32x4 s = {0.f, 0.f, 0.f, 0.f};
    for (int sl = 0; sl < NSLAB; ++sl) s += *(const f32x4*)(base + (size_t)sl * 64 * 4096 + q * 4);
    f32x4 d4 = *(const f32x4*)(dnb + q * 4);
#pragma unroll
    for (int j = 0; j < 4; ++j)
      ctxdm[(size_t)bh * 4096 + (dq + q * 4 + j) * 64 + m] = f2bf(s[j] / d4[j]);
  }
}

// ---------------- K2b: fold Wo with normalized context ---------------------------
// Wfold[b][c][h*64+d] = sum_m Wob[c][h*64+m] * ctxdm[b][h][d][m]
__global__ __launch_bounds__(256) void k_fold(const unsigned short* __restrict__ Wob,
                                              const unsigned short* __restrict__ ctxdm,
                                              unsigned short* __restrict__ Wfold) {
  const int tid = threadIdx.x, lane = tid & 63, wave = tid >> 6;
  const int lr = lane & 15, lg = lane >> 4;
  const int h = blockIdx.x, b = blockIdx.y;
  const int c0 = wave * 64;
  f32x4 zero = {0.f, 0.f, 0.f, 0.f};
  f32x4 acc[4][4];
#pragma unroll
  for (int mt = 0; mt < 4; ++mt)
#pragma unroll
    for (int nt = 0; nt < 4; ++nt) acc[mt][nt] = zero;
  const unsigned short* cdb = ctxdm + (size_t)(b * Hn + h) * 4096;
#pragma unroll
  for (int ks = 0; ks < 2; ++ks) {
    const int kc = ks * 32 + lg * 8;
    bf16x8 af[4], bf4[4];
#pragma unroll
    for (int mt = 0; mt < 4; ++mt)
      af[mt] = asbf(*(const us8*)(Wob + (size_t)(c0 + mt * 16 + lr) * IN + h * 64 + kc));
#pragma unroll
    for (int nt = 0; nt < 4; ++nt)
      bf4[nt] = asbf(*(const us8*)(cdb + (nt * 16 + lr) * 64 + kc));
#pragma unroll
    for (int mt = 0; mt < 4; ++mt)
#pragma unroll
      for (int nt = 0; nt < 4; ++nt) acc[mt][nt] = mfma16(af[mt], bf4[nt], acc[mt][nt]);
  }
  unsigned short* wf = Wfold + (size_t)b * Cn * IN;
#pragma unroll
  for (int mt = 0; mt < 4; ++mt)
#pragma unroll
    for (int nt = 0; nt < 4; ++nt) {
      int c = c0 + mt * 16 + lg * 4;
      int d = h * 64 + nt * 16 + lr;
#pragma unroll
      for (int r = 0; r < 4; ++r) wf[(size_t)(c + r) * IN + d] = f2bf(acc[mt][nt][r]);
    }
}

// ---------------- K3: out = Wfold @ qhT^T + bo (m97-style GEMM, swizzled) --------
__global__ __launch_bounds__(256) void k_wo(const unsigned short* __restrict__ qhT,
                                            const unsigned short* __restrict__ Wfold,
                                            const float* __restrict__ bo,
                                            float* __restrict__ out) {
  __shared__ unsigned short lds[16384];
  const int tid = threadIdx.x, lane = tid & 63, wave = tid >> 6;
  const int lr = lane & 15, lg = lane >> 4;
  const int gl = blockIdx.x * 128;
  const int b = gl >> 13, l0 = gl & 8191;
  const int m0 = blockIdx.y * 128;
  const int wm = (wave >> 1) * 64, wn = (wave & 1) * 64;
  unsigned short* Wt = lds;
  unsigned short* Qt = lds + 8192;

  f32x4 zero = {0.f, 0.f, 0.f, 0.f};
  f32x4 acc[4][4];
#pragma unroll
  for (int mt = 0; mt < 4; ++mt)
#pragma unroll
    for (int nt = 0; nt < 4; ++nt) acc[mt][nt] = zero;

  const int sr = tid >> 3;
  const int scw = (((tid & 7) ^ (sr & 7)) << 3);
  const int rx = (lr & 7);
  const unsigned short* wsrc = Wfold + (size_t)b * Cn * IN + (size_t)(m0 + sr) * IN + scw;
  const unsigned short* qsrc = qhT + (size_t)(b * Ln + l0 + sr) * IN + scw;

  for (int kt = 0; kt < 8; ++kt) {
    const int k0 = kt * 64;
#pragma unroll
    for (int it = 0; it < 4; ++it) {
      gll16(wsrc + (size_t)(it * 32) * IN + k0, Wt + it * 2048 + tid * 8);
      gll16(qsrc + (size_t)(it * 32) * IN + k0, Qt + it * 2048 + tid * 8);
    }
    __syncthreads();
#pragma unroll
    for (int ks = 0; ks < 2; ++ks) {
      const int kc = ((ks * 4 + lg) ^ rx) << 3;
      bf16x8 af[4], bfv[4];
#pragma unroll
      for (int mt = 0; mt < 4; ++mt)
        af[mt] = asbf(*(const us8*)(Wt + (wm + mt * 16 + lr) * 64 + kc));
#pragma unroll
      for (int nt = 0; nt < 4; ++nt)
        bfv[nt] = asbf(*(const us8*)(Qt + (wn + nt * 16 + lr) * 64 + kc));
#pragma unroll
      for (int mt = 0; mt < 4; ++mt)
#pragma unroll
        for (int nt = 0; nt < 4; ++nt) acc[mt][nt] = mfma16(af[mt], bfv[nt], acc[mt][nt]);
    }
    __syncthreads();
  }

#pragma unroll
  for (int mt = 0; mt < 4; ++mt) {
    int c = m0 + wm + mt * 16 + lg * 4;
#pragma unroll
    for (int r = 0; r < 4; ++r) {
      float bb = bo[c + r];
      float* op = out + (size_t)(b * Cn + c + r) * Ln + l0 + wn;
#pragma unroll
      for (int nt = 0; nt < 4; ++nt) op[nt * 16 + lr] = acc[mt][nt][r] + bb;
    }
  }
}

extern "C" void kernel_launch(void* const* d_in, const int* in_sizes, int n_in,
                              void* d_out, int out_size, void* d_ws, size_t ws_size,
                              hipStream_t stream) {
  const float* x = (const float*)d_in[0];
  const float* Wq = (const float*)d_in[1];
  const float* Wk = (const float*)d_in[2];
  const float* Wv = (const float*)d_in[3];
  const float* Wo = (const float*)d_in[4];
  const float* bo = (const float*)d_in[5];
  float* out = (float*)d_out;

  char* ws = (char*)d_ws;
  size_t o = 0;
  unsigned short* xT = (unsigned short*)(ws + o);    o += (size_t)Bn * Ln * Cn * 2;   // 33.5 MB
  unsigned short* Wqkv = (unsigned short*)(ws + o);  o += (size_t)1536 * Cn * 2;      // 768 KB
  unsigned short* Wob = (unsigned short*)(ws + o);   o += (size_t)Cn * IN * 2;        // 256 KB
  unsigned short* qhT = (unsigned short*)(ws + o);   o += (size_t)Bn * Ln * IN * 2;   // 67 MB
  float* ctxP = (float*)(ws + o);                    o += (size_t)NSLAB * 64 * 4096 * 4;  // 16.8 MB
  float* den = (float*)(ws + o);                     o += (size_t)Bn * Hn * 64 * 4;       // 16 KB
  unsigned short* ctxdm = (unsigned short*)(ws + o); o += (size_t)Bn * Hn * 64 * 64 * 2;  // 0.5 MB
  unsigned short* Wfold = (unsigned short*)(ws + o); o += (size_t)Bn * Cn * IN * 2;       // 2 MB

  hipMemsetAsync(den, 0, (size_t)Bn * Hn * 64 * 4, stream);
  k_xt<<<dim3(Ln / 64, Cn / 64, Bn), 256, 0, stream>>>(x, xT);
  k_wcv<<<512, 256, 0, stream>>>(Wq, Wk, Wv, Wo, Wqkv, Wob);
  k_qs<<<dim3(Ln / 128, 4, Bn), 256, 0, stream>>>(xT, Wqkv, qhT);
  k_projkv<<<dim3(Ln / 512, Hn, Bn), 256, 0, stream>>>(xT, Wqkv, ctxP, den);
  k_nrm<<<Bn * Hn, 256, 0, stream>>>(ctxP, den, ctxdm);
  k_fold<<<dim3(Hn, Bn), 256, 0, stream>>>(Wob, ctxdm, Wfold);
  k_wo<<<dim3(Bn * Ln / 128, 2), 256, 0, stream>>>(qhT, Wfold, bo, out);
}